// Round 1
// 2169.163 us; speedup vs baseline: 1.3149x; 1.3149x over previous
//
#include <hip/hip_runtime.h>
#include <math.h>

// ConvLSTM encoder, MI355X. Batch-persistent: one block per batch element,
// 256 threads (4 waves). R10: occupancy push — LDS cut 140,448 -> 81,888 B
// (single-buffer h1 with deferred register writes, c0 state moved to 24
// regs/lane, sx2 stride 40->32) so TWO blocks co-reside per CU
// (__launch_bounds__(256,2), 2 waves/SIMD -> latency hiding; prev all-pipes
// <45% at 1 wave/SIMD). Peephole loads float4-ized (16x fewer scattered
// line touches). L0 bias folded into k=18 weight tap (A=1.0 in sx2).
// Convs = MFMA GEMMs (M=pixels, N=gates*ch, K=im2col taps from LDS).

typedef __bf16 bf16x8 __attribute__((ext_vector_type(8)));
typedef float  f32x4  __attribute__((ext_vector_type(4)));

__device__ __forceinline__ float sigm(float x)  { return 1.f / (1.f + __expf(-x)); }
__device__ __forceinline__ float ftanh(float x) { float e = __expf(2.f * x); return 1.f - 2.f / (e + 1.f); }
__device__ __forceinline__ unsigned short bf16b(float x) {
  __bf16 h = (__bf16)x; unsigned short u; __builtin_memcpy(&u, &h, 2); return u;
}
__device__ __forceinline__ __bf16 ub2bf(unsigned short u) {
  __bf16 h; __builtin_memcpy(&h, &u, 2); return h;
}

// ---------------- workspace layout (bytes) ----------------
#define OFF_WP0  ((size_t)0)          // [2][10][4][64][8] bf16 = 81,920
#define OFF_WP1  ((size_t)81920)      // [4][27][4][64][8] bf16 = 442,368
#define OFF_WFC  ((size_t)524288)     // [168][64][64] bf16 = 1,376,256
#define WS_NEED  ((size_t)1900544)

#define SH0N 9360    // 9*26*40 bf16 per h0 buffer (ping-pong, 2 buffers)
#define SH1N 16848   // 9*26*72 bf16, SINGLE h1 buffer (deferred reg writes)
#define SX2N 5376    // 168*32 bf16 im2col x (k<18 taps + k=18 bias lane)

// ---------------- weight pack kernels (fragment-ordered) ----------------
// wp0f[((chh*10+s)*4+g)*512 + L*8 + e] = W0(n = g*32+chh*16+(L&15),
//   k = s*32+(L>>4)*8+e), K-order: k<32 im2col-x (k<18 real, k==18 bias),
//   k>=32 h-taps.
__global__ void pack_w0(const float* __restrict__ wx0, const float* __restrict__ wh0,
                        const float* __restrict__ bx0, __bf16* __restrict__ dst) {
  int o = blockIdx.x * 256 + threadIdx.x;
  if (o >= 40960) return;
  int e = o & 7, L = (o >> 3) & 63;
  int idx = o >> 9;
  int g = idx & 3, sidx = idx >> 2;
  int s = sidx % 10, chh = sidx / 10;
  int n = g * 32 + chh * 16 + (L & 15);
  int k = s * 32 + (L >> 4) * 8 + e;
  float v = 0.f;
  if (k < 32) {
    if (k < 18) {
      int ky = k / 6, rem = k - ky * 6, kx = rem >> 1, ci = rem & 1;
      v = wx0[(n * 2 + ci) * 9 + ky * 3 + kx];
    } else if (k == 18) {
      v = bx0[n];                      // bias tap: pairs with sx2[pix][18]=1.0
    }
  } else {
    int tk = k - 32, tap = tk >> 5, c = tk & 31;
    v = wh0[(n * 32 + c) * 9 + tap];
  }
  dst[o] = (__bf16)v;
}

// wp1f[((chq*27+s)*4+g)*512 + L*8 + e] = W1(n = g*64+chq*16+(L&15),
//   k = s*32+(L>>4)*8+e), K-order: k<288 x-conv taps, k>=288 h-taps.
__global__ void pack_w1(const float* __restrict__ wx1, const float* __restrict__ wh1,
                        __bf16* __restrict__ dst) {
  int o = blockIdx.x * 256 + threadIdx.x;
  if (o >= 221184) return;
  int e = o & 7, L = (o >> 3) & 63;
  int idx = o >> 9;
  int g = idx & 3, sidx = idx >> 2;
  int s = sidx % 27, chq = sidx / 27;
  int n = g * 64 + chq * 16 + (L & 15);
  int k = s * 32 + (L >> 4) * 8 + e;
  float v;
  if (k < 288) {
    int tap = k >> 5, c = k & 31;
    v = wx1[(n * 32 + c) * 9 + tap];
  } else {
    int tk = k - 288, s2 = tk >> 5, c = tk & 31, tap = s2 >> 1, hf = s2 & 1;
    v = wh1[(n * 64 + hf * 32 + c) * 9 + tap];
  }
  dst[o] = (__bf16)v;
}

// Wfc2[pix][ch][n] bf16 = fc1_w[n][ch*168+pix]
__global__ void pack_wfc(const float* __restrict__ w, __bf16* __restrict__ dst) {
  int o = blockIdx.x * 256 + threadIdx.x;
  if (o >= 168 * 64 * 64) return;
  int pix = o >> 12, ch = (o >> 6) & 63, n = o & 63;
  dst[o] = (__bf16)w[n * 10752 + ch * 168 + pix];
}

// ---------------- the persistent ConvLSTM kernel ----------------
__global__ __launch_bounds__(256, 2) void convlstm_persistent(
    const float* __restrict__ input, const float* __restrict__ x_ex,
    const __bf16* __restrict__ wp0, const __bf16* __restrict__ wp1,
    const __bf16* __restrict__ wfc2,
    const float* __restrict__ bx1,
    const float* __restrict__ wc0, const float* __restrict__ wc1,
    const float* __restrict__ fc1b,
    const float* __restrict__ exw, const float* __restrict__ exb,
    float* __restrict__ out)
{
  // LDS total: 37,440 + 33,696 + 10,752 = 81,888 B -> rounds to 81,920 B
  // (512 B granularity) = exactly half of 160 KiB -> 2 blocks/CU.
  __shared__ __bf16 sh0[2 * SH0N];   // h0 ping-pong, [y][x][40] halo (37,440 B)
  __shared__ __bf16 sh1[SH1N];       // h1 single,    [y][x][72] halo (33,696 B)
  __shared__ __bf16 sx2[SX2N];       // im2col x [pix][32], k<=18 used (10,752 B)

  const int b = blockIdx.x;
  const int t = threadIdx.x;
  const int w = t >> 6, L = t & 63;
  const int lo16 = L & 15, hi4 = L >> 4;

  // ---- zero LDS ----
  {
    int* p0 = (int*)sh0;
    for (int i = t; i < SH0N; i += 256) p0[i] = 0;       // 9360 ints = 37,440 B
    int* p1 = (int*)sh1;
    for (int i = t; i < SH1N / 2; i += 256) p1[i] = 0;   // 8424 ints = 33,696 B
    int* p2 = (int*)sx2;
    for (int i = t; i < SX2N / 2; i += 256) p2[i] = 0;   // 2688 ints = 10,752 B
  }
  __syncthreads();

  // ---- build im2col x2 (time-constant), [pix][32], k = ky*6+kx*2+cin ----
  if (t < 168) {
    int iy = t / 24, ix = t - iy * 24;
    __bf16* dst = sx2 + t * 32;
    for (int ky = 0; ky < 3; ++ky) {
      int y = iy + ky - 1;
      if (y < 0 || y >= 7) continue;
      for (int kx = 0; kx < 3; ++kx) {
        int x = ix + kx - 1;
        if (x < 0 || x >= 24) continue;
        int k0 = ky * 6 + kx * 2;
        dst[k0 + 0] = (__bf16)input[((b * 2 + 0) * 7 + y) * 24 + x];
        dst[k0 + 1] = (__bf16)input[((b * 2 + 1) * 7 + y) * 24 + x];
      }
    }
    dst[18] = (__bf16)1.0f;          // bias lane (pairs with wp0 k==18 = bx0)
  }

  // ---- per-wave / per-lane constants ----
  const int mh = w >> 1, chh = w & 1;
  const int ch0 = chh * 16 + lo16;     // layer-0 channel (0..31)
  const int ch1 = w * 16 + lo16;       // layer-1 channel (0..63)

  const __bf16* w0f = wp0 + chh * 20480 + L * 8;   // + (s*4+g)*512
  const __bf16* w1f = wp1 + w * 55296 + L * 8;     // + (s*4+g)*512

  const float bi1 = bx1[ch1], bf1 = bx1[64 + ch1];
  const float bg1 = bx1[128 + ch1], bo1 = bx1[192 + ch1];

  float c0r[2][3][4];                  // layer-0 cell state, regs (was LDS)
#pragma unroll
  for (int q = 0; q < 2; ++q)
#pragma unroll
    for (int j = 0; j < 3; ++j)
#pragma unroll
      for (int r = 0; r < 4; ++r) c0r[q][j][r] = 0.f;

  float c1r[3][4][4];
#pragma unroll
  for (int p = 0; p < 3; ++p)
#pragma unroll
    for (int j = 0; j < 4; ++j)
#pragma unroll
      for (int r = 0; r < 4; ++r) c1r[p][j][r] = 0.f;

  __syncthreads();   // x2 + zeroed state visible

#pragma unroll 1
  for (int st = 0; st < 7; ++st) {
    const __bf16* h0r = sh0 + (st & 1) * SH0N;
    __bf16*       h0w = sh0 + ((st + 1) & 1) * SH0N;

    unsigned h1d[3][4][2];             // deferred h1(t) writes (48 bf16 packed)

    // ================= layer 0: 2 M-passes, unroll-2 ping-pong =============
#pragma unroll
    for (int q = 0; q < 2; ++q) {
      const int tb = mh * 6 + q * 3;               // first tile of this pass
      const int ntq = (mh == 1 && q == 1) ? 2 : 3; // tile 11 all-dummy
      int b0h[3], b0x[3];
#pragma unroll
      for (int j = 0; j < 3; ++j) {
        int pr = (tb + j) * 16 + lo16;
        if (pr > 167) pr = 167;
        int iy = pr / 24, ix = pr - iy * 24;
        b0h[j] = (iy * 26 + ix) * 40;
        b0x[j] = pr * 32 + hi4 * 8;
      }
      f32x4 a0[4][3];
#pragma unroll
      for (int g = 0; g < 4; ++g)
#pragma unroll
        for (int j = 0; j < 3; ++j) a0[g][j] = (f32x4){0.f, 0.f, 0.f, 0.f};

      auto loadA0 = [&](int s, bf16x8* af) {
        if (s == 0) {
#pragma unroll
          for (int j = 0; j < 3; ++j) af[j] = *(const bf16x8*)(sx2 + b0x[j]);
        } else {
          int tap = s - 1, ky = tap / 3, kx = tap - ky * 3;
          int toff = (ky * 26 + kx) * 40 + hi4 * 8;
#pragma unroll
          for (int j = 0; j < 3; ++j) af[j] = *(const bf16x8*)(h0r + b0h[j] + toff);
        }
      };
      auto loadB0 = [&](int s, bf16x8* bc) {
#pragma unroll
        for (int g = 0; g < 4; ++g)
          bc[g] = *(const bf16x8*)(w0f + (s * 4 + g) * 512);
      };
      auto mfma0 = [&](bf16x8* af, bf16x8* bc) {
#pragma unroll
        for (int j = 0; j < 3; ++j)
#pragma unroll
          for (int g = 0; g < 4; ++g)
            a0[g][j] = __builtin_amdgcn_mfma_f32_16x16x32_bf16(af[j], bc[g], a0[g][j], 0, 0, 0);
      };

      bf16x8 afA[3], afB[3], bcA[4], bcB[4];
      loadA0(0, afA); loadB0(0, bcA);
      loadA0(1, afB); loadB0(1, bcB);
#pragma unroll 1
      for (int s = 0; s < 10; s += 2) {
        mfma0(afA, bcA);
        int s2 = (s + 2 < 10) ? s + 2 : 9;
        loadA0(s2, afA); loadB0(s2, bcA);
        mfma0(afB, bcB);
        int s3 = (s + 3 < 10) ? s + 3 : 9;
        loadA0(s3, afB); loadB0(s3, bcB);
      }

      // epilogue: lane owns (pix = (tb+j)*16 + hi4*4 + r, ch0); c0 in regs;
      // peepholes loaded float4 (p0..p0+3 contiguous, 16B-aligned)
#pragma unroll
      for (int j = 0; j < 3; ++j) {
        int p0 = (tb + j) * 16 + hi4 * 4;
        if (j < ntq && p0 < 168) {
          const float* wpp = wc0 + ch0 * 168 + p0;
          f32x4 w_i = *(const f32x4*)(wpp);
          f32x4 w_f = *(const f32x4*)(wpp + 5376);
          f32x4 w_o = *(const f32x4*)(wpp + 10752);
#pragma unroll
          for (int r = 0; r < 4; ++r) {
            int p = p0 + r;
            float c = c0r[q][j][r];
            float gi = a0[0][j][r];              // bias folded into k=18 tap
            float gf = a0[1][j][r];
            float gc = a0[2][j][r];
            float go = a0[3][j][r];
            float ig = sigm(gi + c * w_i[r]);
            float fg = sigm(gf + c * w_f[r]);
            float cn = fg * c + ig * ftanh(gc);
            float og = sigm(go + cn * w_o[r]);
            float hn = og * ftanh(cn);
            c0r[q][j][r] = cn;
            int iy = p / 24, ix = p - iy * 24;
            h0w[((iy + 1) * 26 + ix + 1) * 40 + ch0] = (__bf16)hn;
          }
        }
      }
    }
    __syncthreads();   // #1: h0(t) visible; h1(t-1) writes from prev step visible

    // ======== layer 1: 3 M-passes x 4 tiles, single-A + dbuf-B =============
#pragma unroll
    for (int p3 = 0; p3 < 3; ++p3) {
      const int ntp = (p3 == 2) ? 3 : 4;           // tile 11 all-dummy
      int b1h0[4], b1h1[4];
#pragma unroll
      for (int j = 0; j < 4; ++j) {
        int pr = (p3 * 4 + j) * 16 + lo16;
        if (pr > 167) pr = 167;
        int iy = pr / 24, ix = pr - iy * 24;
        b1h0[j] = (iy * 26 + ix) * 40;
        b1h1[j] = (iy * 26 + ix) * 72;
      }
      f32x4 a1[4][4];
#pragma unroll
      for (int g = 0; g < 4; ++g)
#pragma unroll
        for (int j = 0; j < 4; ++j) a1[g][j] = (f32x4){0.f, 0.f, 0.f, 0.f};

      auto loadA1 = [&](int s, bf16x8* af) {
        if (s < 9) {
          int ky = s / 3, kx = s - ky * 3;
          int toff = (ky * 26 + kx) * 40 + hi4 * 8;
#pragma unroll
          for (int j = 0; j < 4; ++j) af[j] = *(const bf16x8*)(h0w + b1h0[j] + toff);
        } else {
          int t2 = s - 9, tap = t2 >> 1, hf = t2 & 1;
          int ky = tap / 3, kx = tap - ky * 3;
          int toff = (ky * 26 + kx) * 72 + hf * 32 + hi4 * 8;
#pragma unroll
          for (int j = 0; j < 4; ++j) af[j] = *(const bf16x8*)(sh1 + b1h1[j] + toff);
        }
      };
      auto loadB1 = [&](int s, bf16x8* bc) {
#pragma unroll
        for (int g = 0; g < 4; ++g)
          bc[g] = *(const bf16x8*)(w1f + (s * 4 + g) * 512);
      };
      auto mfma1 = [&](bf16x8* af, bf16x8* bc) {
#pragma unroll
        for (int j = 0; j < 4; ++j) {
          if (j < ntp) {
#pragma unroll
            for (int g = 0; g < 4; ++g)
              a1[g][j] = __builtin_amdgcn_mfma_f32_16x16x32_bf16(af[j], bc[g], a1[g][j], 0, 0, 0);
          }
        }
      };

      bf16x8 af[4], bcA[4], bcB[4];
      loadB1(0, bcA); loadB1(1, bcB);
#pragma unroll 1
      for (int s = 0; s < 27; s += 2) {
        loadA1(s, af);
        mfma1(af, bcA);
        loadB1((s + 2 < 27) ? s + 2 : 26, bcA);
        if (s + 1 < 27) {
          loadA1(s + 1, af);
          mfma1(af, bcB);
          loadB1((s + 3 < 27) ? s + 3 : 26, bcB);
        }
      }

      // epilogue: lane owns (pix = (p3*4+j)*16 + hi4*4 + r, ch1);
      // h1(t) deferred into packed regs (sh1 still being read by others)
#pragma unroll
      for (int j = 0; j < 4; ++j) {
        int p0 = (p3 * 4 + j) * 16 + hi4 * 4;
        if (j < ntp && p0 < 168) {
          const float* wpp = wc1 + ch1 * 168 + p0;
          f32x4 w_i = *(const f32x4*)(wpp);
          f32x4 w_f = *(const f32x4*)(wpp + 10752);
          f32x4 w_o = *(const f32x4*)(wpp + 21504);
#pragma unroll
          for (int rp = 0; rp < 2; ++rp) {
            unsigned pk = 0;
#pragma unroll
            for (int h = 0; h < 2; ++h) {
              int r = rp * 2 + h;
              float c = c1r[p3][j][r];
              float gi = a1[0][j][r] + bi1;
              float gf = a1[1][j][r] + bf1;
              float gc = a1[2][j][r] + bg1;
              float go = a1[3][j][r] + bo1;
              float ig = sigm(gi + c * w_i[r]);
              float fg = sigm(gf + c * w_f[r]);
              float cn = fg * c + ig * ftanh(gc);
              float og = sigm(go + cn * w_o[r]);
              float hn = og * ftanh(cn);
              c1r[p3][j][r] = cn;
              pk |= (unsigned)bf16b(hn) << (h * 16);
            }
            h1d[p3][j][rp] = pk;
          }
        }
      }
    }
    __syncthreads();   // #2: all sh1 (h1(t-1)) reads done

    // ---- flush deferred h1(t) into the single sh1 buffer ----
#pragma unroll
    for (int p3 = 0; p3 < 3; ++p3) {
      const int ntp = (p3 == 2) ? 3 : 4;
#pragma unroll
      for (int j = 0; j < 4; ++j) {
        int p0 = (p3 * 4 + j) * 16 + hi4 * 4;
        if (j < ntp && p0 < 168) {
#pragma unroll
          for (int rp = 0; rp < 2; ++rp) {
            unsigned v = h1d[p3][j][rp];
#pragma unroll
            for (int h = 0; h < 2; ++h) {
              int p = p0 + rp * 2 + h;
              int iy = p / 24, ix = p - iy * 24;
              sh1[((iy + 1) * 26 + ix + 1) * 72 + ch1] =
                  ub2bf((unsigned short)(v >> (h * 16)));
            }
          }
        }
      }
    }
    // no barrier here: next step's barrier #1 precedes any sh1 read
  }
  __syncthreads();     // h1(7) writes visible before FC reads

  // ================= FC heads (h1 final in sh1) =================
  {
    const __bf16* h1f = sh1;
    const int o = t & 3, pg = t >> 2;    // o: 16 n's (o*16..); pg 0..63
    float part[16];
#pragma unroll
    for (int q = 0; q < 16; ++q) part[q] = 0.f;
#pragma unroll 1
    for (int jj = 0; jj < 3; ++jj) {
      int p = pg + 64 * jj;
      if (p < 168) {
        int iy = p / 24, ix = p - iy * 24;
        const __bf16* hrow = h1f + ((iy + 1) * 26 + ix + 1) * 72;
        const __bf16* wrow = wfc2 + (size_t)p * 4096 + o * 16;
        for (int ch = 0; ch < 64; ++ch) {
          float hv = (float)hrow[ch];
          bf16x8 wv0 = *(const bf16x8*)(wrow + ch * 64);
          bf16x8 wv1 = *(const bf16x8*)(wrow + ch * 64 + 8);
#pragma unroll
          for (int q = 0; q < 8; ++q) {
            part[q] += hv * (float)wv0[q];
            part[8 + q] += hv * (float)wv1[q];
          }
        }
      }
    }
    float* sacc = (float*)sh0;   // h0 buffers dead after last step; 16 KB needed
    __syncthreads();
#pragma unroll
    for (int q = 0; q < 16; ++q) sacc[pg * 64 + o * 16 + q] = part[q];
    __syncthreads();
    if (t < 64) {
      float s = fc1b[t];
      for (int pg2 = 0; pg2 < 64; ++pg2) s += sacc[pg2 * 64 + t];
      out[(size_t)b * 128 + t] = fmaxf(s, 0.f);
    } else if (t < 128) {
      int j = t - 64;
      float s = exb[j];
      for (int k = 0; k < 24; ++k) s += x_ex[b * 24 + k] * exw[j * 24 + k];
      out[(size_t)b * 128 + 64 + j] = fmaxf(s, 0.f);
    }
  }
}

// ---------------- launcher ----------------
extern "C" void kernel_launch(void* const* d_in, const int* in_sizes, int n_in,
                              void* d_out, int out_size, void* d_ws, size_t ws_size,
                              hipStream_t stream) {
  const float* input = (const float*)d_in[0];
  const float* x_ex  = (const float*)d_in[1];
  const float* Wx0   = (const float*)d_in[2];
  const float* bx0   = (const float*)d_in[3];
  const float* Wh0   = (const float*)d_in[4];
  const float* Wc0   = (const float*)d_in[5];
  const float* Wx1   = (const float*)d_in[6];
  const float* bx1   = (const float*)d_in[7];
  const float* Wh1   = (const float*)d_in[8];
  const float* Wc1   = (const float*)d_in[9];
  const float* fc1w  = (const float*)d_in[10];
  const float* fc1b  = (const float*)d_in[11];
  const float* exw   = (const float*)d_in[12];
  const float* exb   = (const float*)d_in[13];
  (void)in_sizes; (void)n_in;

  if (ws_size < WS_NEED) {
    hipMemsetAsync(d_out, 0, (size_t)out_size * 4, stream);
    return;
  }

  char* ws = (char*)d_ws;
  __bf16* wp0  = (__bf16*)(ws + OFF_WP0);
  __bf16* wp1  = (__bf16*)(ws + OFF_WP1);
  __bf16* wfc2 = (__bf16*)(ws + OFF_WFC);

  pack_w0<<<160, 256, 0, stream>>>(Wx0, Wh0, bx0, wp0);
  pack_w1<<<864, 256, 0, stream>>>(Wx1, Wh1, wp1);
  pack_wfc<<<2688, 256, 0, stream>>>(fc1w, wfc2);

  convlstm_persistent<<<2048, 256, 0, stream>>>(
      input, x_ex, wp0, wp1, wfc2, bx1, Wc0, Wc1, fc1b, exw, exb,
      (float*)d_out);
}